// Round 2
// baseline (83.240 us; speedup 1.0000x reference)
//
#include <hip/hip_runtime.h>
#include <math.h>

// HD95 (mean over batch of 95th-percentile Hausdorff) on MI355X.
// Problem constants (from reference): 2 images, 96x96, cdist block B=1000,
// padded capacity K=10000, nb=10 blocks.
//
// Exactness argument:
//  - Coordinates are integers in [0,95]; the reference's f32
//    |a|^2+|b|^2-2ab arithmetic is exact (all intermediates < 2^24), so every
//    distance is sqrt of an exact integer d^2 in [0,18050].
//  - Therefore the 95th percentile over pooled block-mins can be read off an
//    integer histogram of d^2 (no sort). Finite-count is closed-form:
//    n = cnt_p*ceil(cnt_t/1000) + cnt_t*ceil(cnt_p/1000).
//  - nanquantile emulation: pos = 0.95f*(n-1) in f32; result =
//    v[floor]*(1-g) + v[min(floor+1,n-1)]*g  (matches jnp linear interp).

#define IMG_W 96
#define NPIX  9216
#define KCAP  10000      // padded points per (which,img): ceil(9216/1000)*1000
#define BSZ   1000       // cdist tiling block
#define HB    18432      // histogram stride (1024*18 >= 18051 bins)
#define SENTI ((30000u << 16) | 30000u)   // far sentinel coord (x=30000,y=30000)

// Workspace layout (byte offsets are path-independent; host only uses these):
//   [0      , 320000) : packed coords cxy[4][KCAP]  (u32 (x<<16|y) or float2)
//   [320000 , 320016) : int cnt[4]   (which*2+img; which 0=pred 1=true)
//   [320064 , 467520) : u32 hist[2][HB]

#ifdef __HIP_DEVICE_COMPILE__
#if __has_builtin(__builtin_amdgcn_sdot2)
#define USE_SDOT2 1
#else
#define USE_SDOT2 0
#endif
#else
#define USE_SDOT2 0
#endif

typedef short short2v __attribute__((ext_vector_type(2)));

static __device__ __forceinline__ short2v as_s2(unsigned u) {
    short2v r;
    __builtin_memcpy(&r, &u, 4);
    return r;
}

// Inclusive block scan over 1024 threads: wave shfl scan + 16-wide cross-wave
// scan. wsh must have >=16 ints; wsh[15] holds the block total afterwards.
static __device__ __forceinline__ int block_scan1024(int val, int t, int* wsh) {
    int lane = t & 63, w = t >> 6;
    int v = val;
#pragma unroll
    for (int off = 1; off < 64; off <<= 1) {
        int u = __shfl_up(v, off);
        if (lane >= off) v += u;
    }
    if (lane == 63) wsh[w] = v;
    __syncthreads();
    if (w == 0) {
        int x = (lane < 16) ? wsh[lane] : 0;
#pragma unroll
        for (int off = 1; off < 16; off <<= 1) {
            int u = __shfl_up(x, off);
            if (lane >= off && lane < 16) x += u;
        }
        if (lane < 16) wsh[lane] = x;
    }
    __syncthreads();
    return (w ? wsh[w - 1] : 0) + v;
}

// ---------------------------------------------------------------------------
// Compaction: one block per (img,which). 1024 threads x 9 elements = 9216,
// row-major order preserved (thread t owns [9t,9t+9)), matching jnp.nonzero.
// Writes packed coords, sentinel-pads to KCAP, writes counts, and zeroes the
// global histograms (so no separate memset launch is needed).
// ---------------------------------------------------------------------------
__global__ __launch_bounds__(1024) void hd95_compact(const float* __restrict__ inp,
                                                     const float* __restrict__ tgt,
                                                     void* __restrict__ cxybuf,
                                                     int* __restrict__ cntbuf,
                                                     unsigned* __restrict__ hist)
{
    int img = blockIdx.x >> 1;
    int which = blockIdx.x & 1;
    const float* src = (which ? tgt : inp) + img * NPIX;
    int t = threadIdx.x;

    // zero hist: 4 blocks x 1024 threads cover 2*HB = 36864 words (9 each)
    for (int k = blockIdx.x * 1024 + t; k < 2 * HB; k += 4096) hist[k] = 0u;

    int base = t * 9;
    unsigned m9 = 0;
    int lc = 0;
#pragma unroll
    for (int j = 0; j < 9; ++j) {
        bool nz = src[base + j] > 0.5f;
        m9 |= (nz ? 1u : 0u) << j;
        lc += nz ? 1 : 0;
    }
    __shared__ int wsh[16];
    int incl = block_scan1024(lc, t, wsh);
    int pos = incl - lc;
    int total = wsh[15];

#if USE_SDOT2
    unsigned* out = (unsigned*)cxybuf + (which * 2 + img) * KCAP;
#pragma unroll
    for (int j = 0; j < 9; ++j)
        if (m9 & (1u << j)) {
            int fi = base + j;
            out[pos++] = ((unsigned)(fi / IMG_W) << 16) | (unsigned)(fi % IMG_W);
        }
    for (int k = total + t; k < KCAP; k += 1024) out[k] = SENTI;
#else
    float2* out = (float2*)cxybuf + (which * 2 + img) * KCAP;
#pragma unroll
    for (int j = 0; j < 9; ++j)
        if (m9 & (1u << j)) {
            int fi = base + j;
            out[pos++] = make_float2((float)(fi / IMG_W), (float)(fi % IMG_W));
        }
    for (int k = total + t; k < KCAP; k += 1024) out[k] = make_float2(30000.f, 30000.f);
#endif
    if (t == 1023) cntbuf[which * 2 + img] = total;
}

// ---------------------------------------------------------------------------
// Block-min + histogram. blockIdx.z = dir*2+img (dir 0: A=pred,B=true -> row
// mins; dir 1: A=true,B=pred -> col mins). Each block = 4 waves; a work item
// is (64 A-points, one B-block of 1000). The B block is staged padded to 1024
// (sentinel), wave s scans sub-chunk [256s,256s+256) via uniform ds_read_b128
// broadcasts; mins combine across waves in LDS; wave 0 deposits per-A-point
// min-d^2 into the global histogram with wave-aggregated atomics (loop over
// distinct keys -> ~10-25 atomics per 64 values, deterministic integer adds).
// ---------------------------------------------------------------------------
__global__ __launch_bounds__(256) void hd95_blockmin(const void* __restrict__ cxybuf,
                                                     const int* __restrict__ cntbuf,
                                                     unsigned* __restrict__ hist)
{
    int img = blockIdx.z & 1;
    int dir = blockIdx.z >> 1;
    int cntA = cntbuf[dir * 2 + img];
    int cntB = cntbuf[(1 - dir) * 2 + img];
    int nchunk = (cntA + 63) >> 6;
    int nbb = (cntB + BSZ - 1) / BSZ;
    int items = nchunk * nbb;

    int t = threadIdx.x, s = t >> 6, lane = t & 63;
    unsigned* gh = hist + img * HB;

#if USE_SDOT2
    __shared__ uint4 Bl4[4][64];        // 4 sub-chunks x 64 uint4 = 1024 coords
    const unsigned* A = (const unsigned*)cxybuf + (dir * 2 + img) * KCAP;
    const unsigned* B = (const unsigned*)cxybuf + ((1 - dir) * 2 + img) * KCAP;
#else
    __shared__ float2 Blf[4][256];
    const float2* A = (const float2*)cxybuf + (dir * 2 + img) * KCAP;
    const float2* B = (const float2*)cxybuf + ((1 - dir) * 2 + img) * KCAP;
#endif
    __shared__ int lmin[4][64];

    for (int it = blockIdx.x; it < items; it += gridDim.x) {
        int chunk = it % nchunk;
        int bb = it / nchunk;

        // ---- stage B block (padded to 1024 with sentinel) ----
#if USE_SDOT2
        {
            const uint4* Bg = (const uint4*)(B + bb * BSZ);   // 4000B offset, 16B aligned
            uint4 v;
            if (t < 250) v = Bg[t];
            else v = make_uint4(SENTI, SENTI, SENTI, SENTI);
            Bl4[t >> 6][t & 63] = v;
        }
#else
        for (int j = 0; j < 4; ++j) {
            int k = t + 256 * j;
            Blf[k >> 8][k & 255] = (k < BSZ) ? B[bb * BSZ + k] : make_float2(30000.f, 30000.f);
        }
#endif
        __syncthreads();

        int aIdx = chunk * 64 + lane;    // < KCAP always (sentinel-padded)
        int dmin;
#if USE_SDOT2
        {
            short2v av = as_s2(A[aIdx]);
            int dm = 0x7fffffff;
            const uint4* row = &Bl4[s][0];
#pragma unroll 4
            for (int c4 = 0; c4 < 64; ++c4) {
                uint4 q = row[c4];       // uniform address: LDS broadcast
                short2v d0 = av - as_s2(q.x);
                dm = min(dm, __builtin_amdgcn_sdot2(d0, d0, 0, false));
                short2v d1 = av - as_s2(q.y);
                dm = min(dm, __builtin_amdgcn_sdot2(d1, d1, 0, false));
                short2v d2 = av - as_s2(q.z);
                dm = min(dm, __builtin_amdgcn_sdot2(d2, d2, 0, false));
                short2v d3 = av - as_s2(q.w);
                dm = min(dm, __builtin_amdgcn_sdot2(d3, d3, 0, false));
            }
            dmin = dm;
        }
#else
        {
            float2 fa = A[aIdx];
            float dm = 3.9e9f;
            const float2* row = &Blf[s][0];
#pragma unroll 4
            for (int c = 0; c < 256; ++c) {
                float dx = fa.x - row[c].x;
                float dy = fa.y - row[c].y;
                dm = fminf(dm, fmaf(dx, dx, dy * dy));
            }
            dmin = (int)dm;
        }
#endif
        lmin[s][lane] = dmin;
        __syncthreads();

        if (s == 0) {
            int m = min(min(lmin[0][lane], lmin[1][lane]),
                        min(lmin[2][lane], lmin[3][lane]));
            bool valid = aIdx < cntA;
            unsigned long long act = __ballot(valid);
            while (act) {
                int leader = (int)__ffsll(act) - 1;
                int lkey = __shfl(m, leader);
                unsigned long long ms = __ballot(valid && (m == lkey));
                if (lane == leader) atomicAdd(&gh[lkey], (unsigned)__popcll(ms));
                act &= ~ms;
            }
        }
        __syncthreads();   // protect Bl/lmin before next item's staging
    }
}

// ---------------------------------------------------------------------------
// Quantile for both images + final mean, one 1024-thread block.
// Emulates jnp.nanquantile(vals, 0.95) exactly (f32 index math, linear
// interp, values = sqrt(bin)), then mean over valid images (inf if none).
// ---------------------------------------------------------------------------
__global__ __launch_bounds__(1024) void hd95_quantile(const unsigned* __restrict__ hist,
                                                      const int* __restrict__ cntbuf,
                                                      float* __restrict__ out)
{
    __shared__ int wsh[16];
    __shared__ float vv[2];
    __shared__ float hdsh[2];
    int t = threadIdx.x;

    for (int img = 0; img < 2; ++img) {
        int cp = cntbuf[img], ct = cntbuf[2 + img];
        if (cp > 0 && ct > 0) {
            int n = cp * ((ct + BSZ - 1) / BSZ) + ct * ((cp + BSZ - 1) / BSZ);
            const unsigned* h = hist + img * HB;
            int base = t * 18, lsum = 0;
#pragma unroll
            for (int j = 0; j < 18; ++j) lsum += (int)h[base + j];
            int incl = block_scan1024(lsum, t, wsh);
            int excl = incl - lsum;

            float pos = 0.95f * (float)(n - 1);
            int kk = (int)floorf(pos);
            float g = pos - (float)kk;
            int r0 = kk, r1 = min(kk + 1, n - 1);

            if (r0 >= excl && r0 < excl + lsum) {
                int loc = r0 - excl;
                for (int j = 0; j < 18; ++j) {
                    int c = (int)h[base + j];
                    if (loc < c) { vv[0] = sqrtf((float)(base + j)); break; }
                    loc -= c;
                }
            }
            if (r1 >= excl && r1 < excl + lsum) {
                int loc = r1 - excl;
                for (int j = 0; j < 18; ++j) {
                    int c = (int)h[base + j];
                    if (loc < c) { vv[1] = sqrtf((float)(base + j)); break; }
                    loc -= c;
                }
            }
            __syncthreads();
            if (t == 0) hdsh[img] = vv[0] * (1.0f - g) + vv[1] * g;
        } else {
            if (t == 0) hdsh[img] = 0.0f;
        }
        __syncthreads();
    }

    if (t == 0) {
        bool ok0 = (cntbuf[0] > 0) && (cntbuf[2] > 0);
        bool ok1 = (cntbuf[1] > 0) && (cntbuf[3] > 0);
        int nn = (ok0 ? 1 : 0) + (ok1 ? 1 : 0);
        float ssum = (ok0 ? hdsh[0] : 0.0f) + (ok1 ? hdsh[1] : 0.0f);
        out[0] = (nn > 0) ? (ssum / (float)nn) : INFINITY;
    }
}

extern "C" void kernel_launch(void* const* d_in, const int* in_sizes, int n_in,
                              void* d_out, int out_size, void* d_ws, size_t ws_size,
                              hipStream_t stream)
{
    const float* inp = (const float*)d_in[0];
    const float* tgt = (const float*)d_in[1];
    char* ws = (char*)d_ws;

    void*     cxy  = (void*)ws;                  // up to 320000 B (both paths fit)
    int*      cnt  = (int*)(ws + 320000);        // 16 B
    unsigned* hist = (unsigned*)(ws + 320064);   // 147456 B
    float*    out  = (float*)d_out;

    hd95_compact<<<4, 1024, 0, stream>>>(inp, tgt, cxy, cnt, hist);
    hd95_blockmin<<<dim3(512, 1, 4), 256, 0, stream>>>(cxy, cnt, hist);
    hd95_quantile<<<1, 1024, 0, stream>>>(hist, cnt, out);
}